// Round 7
// baseline (1402.917 us; speedup 1.0000x reference)
//
#include <hip/hip_runtime.h>
#include <hip/hip_bf16.h>

typedef __attribute__((ext_vector_type(4))) float f32x4;
typedef __attribute__((ext_vector_type(8))) short short8;
typedef __attribute__((ext_vector_type(4))) unsigned int u32x4;
typedef __attribute__((ext_vector_type(4))) unsigned short u16x4;

static __device__ __forceinline__ unsigned short f2bf(float f){
  unsigned u = __builtin_bit_cast(unsigned, f);
  u += 0x7FFFu + ((u >> 16) & 1u);
  return (unsigned short)(u >> 16);
}
static __device__ __forceinline__ float bf2f(unsigned short b){
  return __builtin_bit_cast(float, ((unsigned)b) << 16);
}
static __device__ __forceinline__ f32x4 mfma16(short8 a, short8 b, f32x4 c){
  return __builtin_amdgcn_mfma_f32_16x16x32_bf16(a, b, c, 0, 0, 0);
}
static __device__ __forceinline__ float rcpf(float x){ return __builtin_amdgcn_rcpf(x); }
static __device__ __forceinline__ float sigf(float x){ return rcpf(1.f + __expf(-x)); }
static __device__ __forceinline__ float tanhfast(float x){
  float e = __expf(2.f*x);
  return (e - 1.f) * rcpf(e + 1.f);
}

// ---------------------------------------------------------------------------
// fp32 -> bf16 weight conversion (head_W + 7 small matrices of 196608 elems)
// ---------------------------------------------------------------------------
__global__ __launch_bounds__(256) void k_cvt(
    const float* __restrict__ sh, unsigned short* __restrict__ dh,
    const float* __restrict__ s0, const float* __restrict__ s1,
    const float* __restrict__ s2, const float* __restrict__ s3,
    const float* __restrict__ s4, const float* __restrict__ s5,
    const float* __restrict__ s6,
    unsigned short* __restrict__ d0, unsigned short* __restrict__ d1,
    unsigned short* __restrict__ d2, unsigned short* __restrict__ d3,
    unsigned short* __restrict__ d4, unsigned short* __restrict__ d5,
    unsigned short* __restrict__ d6)
{
  const long NH4 = 2048000;   // head: 8,192,000 floats / 4
  const long NS4 = 49152;     // small: 196,608 floats / 4
  const long total = NH4 + 7*NS4;
  for (long idx = (long)blockIdx.x*blockDim.x + threadIdx.x; idx < total;
       idx += (long)gridDim.x*blockDim.x) {
    const float* s; unsigned short* d; long off;
    if (idx < NH4) { s = sh; d = dh; off = idx; }
    else {
      long r = idx - NH4; int mat = (int)(r / NS4); off = r - (long)mat*NS4;
      switch (mat) {
        case 0: s=s0; d=d0; break;  case 1: s=s1; d=d1; break;
        case 2: s=s2; d=d2; break;  case 3: s=s3; d=d3; break;
        case 4: s=s4; d=d4; break;  case 5: s=s5; d=d5; break;
        default: s=s6; d=d6; break;
      }
    }
    f32x4 v = ((const f32x4*)s)[off];
    u16x4 o2;
    o2[0]=f2bf(v[0]); o2[1]=f2bf(v[1]); o2[2]=f2bf(v[2]); o2[3]=f2bf(v[3]);
    ((u16x4*)d)[off] = o2;
  }
}

// ---------------------------------------------------------------------------
// Generic MFMA GEMM: out[M][N] = gatherA[M][Ktot] @ W[N][Ktot]^T + bias
// ---------------------------------------------------------------------------
template<int TN, int TS, int EPI>
__global__ __launch_bounds__(256) void k_gemm(
    const float* __restrict__ tabA, int ldA,
    const float* __restrict__ tabB2, int ldB2, int K1,
    const int* __restrict__ ids,
    const unsigned short* __restrict__ W,   // [N][Ktot] bf16
    const float* __restrict__ bias,         // [N]
    int M, int Ktot,
    void* __restrict__ outp, int ldOut)
{
  const int bm = blockIdx.x, bn = blockIdx.y;
  const int tid = threadIdx.x;
  const int lane = tid & 63, w = tid >> 6;
  const int l15 = lane & 15, l4 = lane >> 4;

  const int r_g = bm*64 + w*16 + l15;
  const int r_c = (r_g < M) ? r_g : (M-1);
  long row_src;
  if (ids) { int ii = (r_c / TN) * TS + (r_c % TN); row_src = ids[ii]; }
  else row_src = r_c;

  const int kchunk = l4 * 8;
  const int ncol0 = bn*128 + l15;

  f32x4 acc[8];
  #pragma unroll
  for (int i=0;i<8;i++){ f32x4 z4 = {0.f,0.f,0.f,0.f}; acc[i]=z4; }

  const int KB = Ktot >> 5;
  for (int kb = 0; kb < KB; ++kb) {
    int k = kb*32 + kchunk;
    const float* ap;
    if (tabB2 && k >= K1) ap = tabB2 + row_src*(long)ldB2 + (k - K1);
    else                  ap = tabA  + row_src*(long)ldA  + k;
    f32x4 a0 = *(const f32x4*)ap;
    f32x4 a1 = *(const f32x4*)(ap + 4);
    short8 afr;
    afr[0]=(short)f2bf(a0[0]); afr[1]=(short)f2bf(a0[1]);
    afr[2]=(short)f2bf(a0[2]); afr[3]=(short)f2bf(a0[3]);
    afr[4]=(short)f2bf(a1[0]); afr[5]=(short)f2bf(a1[1]);
    afr[6]=(short)f2bf(a1[2]); afr[7]=(short)f2bf(a1[3]);
    #pragma unroll
    for (int ct=0; ct<8; ++ct) {
      int n = ncol0 + ct*16;
      short8 bfr = *(const short8*)(W + (long)n*Ktot + k);
      acc[ct] = mfma16(afr, bfr, acc[ct]);
    }
  }

  #pragma unroll
  for (int ct=0; ct<8; ++ct) {
    int n = ncol0 + ct*16;
    float bv = bias[n];
    #pragma unroll
    for (int q=0; q<4; ++q) {
      int rr = bm*64 + w*16 + l4*4 + q;
      if (rr < M) {
        float v = acc[ct][q] + bv;
        if (EPI == 1) ((float*)outp)[(long)rr*ldOut + n] = tanhfast(v);
        else ((unsigned short*)outp)[(long)rr*ldOut + n] = f2bf(v);
      }
    }
  }
}

// ---------------------------------------------------------------------------
// Distributed GRU recurrence.
//   One recurrence of 16 rows is split across 8 blocks (128 thr / 2 waves).
//   Block (g, ub=blockIdx&7) owns 32 hidden units (all 3 gates), whose
//   Whh slice (96 cols x 256 k = 48KB) lives in LDS -- no per-step weight
//   restream (the round-2..5 register-residency attempts all failed: the
//   allocator reloads from L2 at ~5800 cy/step).
//   Gate-colocated column order => MFMA C layout (col=lane&15) gives each
//   lane r,z,n for the SAME (row,unit): gate math is lane-local.
//   h state: global double buffer hbuf[2][G][16][256] bf16, parity by t.
//   Per-step sync: agent-scope atomic arrive + relaxed spin + acquire fence
//   (cross-XCD safe). Flags are per-step counters, memset 0 per launch.
// ---------------------------------------------------------------------------
__global__ __launch_bounds__(128) void k_gruD(
    const unsigned short* __restrict__ Whh,  // [768][256] bf16
    const float* __restrict__ bhh,           // [768]
    const unsigned short* __restrict__ xg,   // [(row*T+t)][768] bf16 (bih inc.)
    const int* __restrict__ mask,            // [(row*T+t)] or null
    int hpre,                                // 1 => hbuf buf0 pre-filled
    unsigned short* __restrict__ hbuf,       // [2][G][16][256] bf16
    int* __restrict__ flags,                 // [G][T+1], zeroed
    unsigned short* __restrict__ outs,       // [(row*T+t)][256] bf16 or null
    float* __restrict__ hNf,                 // [row][256] f32 or null
    unsigned short* __restrict__ hNbf,       // [16][256] bf16 or null
    int T, int G)
{
  __shared__ unsigned short Wl[2*3*8*64*8];  // [w][gt][kb][lane]x8 = 48KB

  const int tid  = threadIdx.x;
  const int w    = tid >> 6;                 // wave 0/1
  const int lane = tid & 63;
  const int l15  = lane & 15, l4 = lane >> 4;
  const int g    = blockIdx.x >> 3;
  const int ub   = blockIdx.x & 7;
  const int u    = ub*32 + w*16 + l15;       // this lane's hidden unit

  // stage Whh slice -> LDS (B-frag layout: lane=(col l15, kslice l4))
  #pragma unroll
  for (int gt=0; gt<3; ++gt)
    #pragma unroll
    for (int kb=0; kb<8; ++kb)
      *(short8*)&Wl[(((w*3+gt)*8+kb)*64 + lane)*8] =
          *(const short8*)(Whh + ((long)gt*256 + u)*256 + kb*32 + l4*8);

  const float br = bhh[u], bz = bhh[256+u], bn = bhh[512+u];
  unsigned short* hb0 = hbuf + (size_t)g*4096;
  unsigned short* hb1 = hbuf + (size_t)(G + g)*4096;
  int* flg = flags + g*(T+1);

  if (!hpre) {
    int r = tid >> 3, c = tid & 7;           // 16 rows x 8 unit-quads
    int u0 = ub*32 + c*4;
    u16x4 z4 = {0,0,0,0};
    *(u16x4*)&hb0[r*256 + u0] = z4;
    __syncthreads();
    if (tid == 0) {
      __hip_atomic_fetch_add(flg, 1, __ATOMIC_RELEASE, __HIP_MEMORY_SCOPE_AGENT);
      while (__hip_atomic_load(flg, __ATOMIC_RELAXED, __HIP_MEMORY_SCOPE_AGENT) < 8) {}
    }
    __builtin_amdgcn_fence(__ATOMIC_ACQUIRE, "agent");
  }
  __syncthreads();

  for (int t=0; t<T; ++t) {
    const unsigned short* hc = (t&1) ? hb1 : hb0;
    unsigned short*       hn = (t&1) ? hb0 : hb1;

    // A-fragments: full h tile (16x256) read by every block
    short8 af[8];
    #pragma unroll
    for (int kb=0; kb<8; ++kb)
      af[kb] = *(const short8*)(hc + l15*256 + kb*32 + l4*8);

    f32x4 a0={0.f,0.f,0.f,0.f}, a1={0.f,0.f,0.f,0.f}, a2={0.f,0.f,0.f,0.f};
    #pragma unroll
    for (int kb=0; kb<8; ++kb) {
      a0 = mfma16(af[kb], *(const short8*)&Wl[(((w*3+0)*8+kb)*64+lane)*8], a0);
      a1 = mfma16(af[kb], *(const short8*)&Wl[(((w*3+1)*8+kb)*64+lane)*8], a1);
      a2 = mfma16(af[kb], *(const short8*)&Wl[(((w*3+2)*8+kb)*64+lane)*8], a2);
    }

    #pragma unroll
    for (int q=0; q<4; ++q) {
      int r = l4*4 + q;
      long row  = (long)g*16 + r;
      long xrow = row*T + t;
      const unsigned short* xp = xg + xrow*768;
      float xr = bf2f(xp[u]);
      float xz = bf2f(xp[256+u]);
      float xn = bf2f(xp[512+u]);
      float hold = bf2f(hc[r*256 + u]);
      float rr = sigf(xr + a0[q] + br);
      float zz = sigf(xz + a1[q] + bz);
      float nn = tanhfast(xn + rr*(a2[q] + bn));
      float hv = nn + zz*(hold - nn);
      if (mask && !mask[xrow]) hv = hold;
      unsigned short hb = f2bf(hv);
      hn[r*256 + u] = hb;
      if (outs) outs[xrow*256 + u] = hb;
      if (t == T-1) {
        if (hNf)  hNf[row*256 + u] = hv;
        if (hNbf) hNbf[r*256 + u]  = hb;
      }
    }

    __syncthreads();   // both waves drain vmcnt before the release (HIP barrier semantics)
    if (tid == 0) {
      __hip_atomic_fetch_add(flg + (t+1), 1, __ATOMIC_RELEASE, __HIP_MEMORY_SCOPE_AGENT);
      while (__hip_atomic_load(flg + (t+1), __ATOMIC_RELAXED, __HIP_MEMORY_SCOPE_AGENT) < 8) {}
    }
    __builtin_amdgcn_fence(__ATOMIC_ACQUIRE, "agent");
    __syncthreads();
  }
}

// ---------------------------------------------------------------------------
// Memory scan: per batch b (block, 1 wave): 32 steps of attention-write memory.
// ---------------------------------------------------------------------------
__global__ __launch_bounds__(64) void k_mem(
    const float* __restrict__ z,         // [512][256] rows b*32+t
    const float* __restrict__ mem_init,  // [16][256]
    float* __restrict__ z2)              // [512][256]
{
  const int b = blockIdx.x;
  const int lane = threadIdx.x;
  float mem[16][4];
  #pragma unroll
  for (int m=0; m<16; ++m) {
    f32x4 v = *(const f32x4*)(mem_init + m*256 + lane*4);
    mem[m][0]=v[0]; mem[m][1]=v[1]; mem[m][2]=v[2]; mem[m][3]=v[3];
  }
  for (int t=0; t<32; ++t) {
    f32x4 q = *(const f32x4*)(z + ((long)b*32 + t)*256 + lane*4);
    float s[16];
    #pragma unroll
    for (int m=0; m<16; ++m)
      s[m] = mem[m][0]*q[0] + mem[m][1]*q[1] + mem[m][2]*q[2] + mem[m][3]*q[3];
    #pragma unroll
    for (int st=1; st<64; st<<=1) {
      #pragma unroll
      for (int m=0; m<16; ++m) s[m] += __shfl_xor(s[m], st, 64);
    }
    float mx = -1e30f;
    #pragma unroll
    for (int m=0; m<16; ++m) { s[m] *= 0.0625f; mx = fmaxf(mx, s[m]); }
    float sum = 0.f;
    #pragma unroll
    for (int m=0; m<16; ++m) { s[m] = __expf(s[m]-mx); sum += s[m]; }
    float inv = rcpf(sum);
    f32x4 ro = {0.f,0.f,0.f,0.f};
    #pragma unroll
    for (int m=0; m<16; ++m) {
      float wm = s[m]*inv;
      #pragma unroll
      for (int c=0; c<4; ++c) {
        ro[c] += wm * mem[m][c];
        mem[m][c] += wm * (q[c] - mem[m][c]);
      }
    }
    f32x4 o = q + ro;
    *(f32x4*)(z2 + ((long)b*32 + t)*256 + lane*4) = o;
  }
}

// ---------------------------------------------------------------------------
// Head GEMM: out[2032][32000] = A[2032][256]bf16 @ Bw[32000][256]^T + bias
// ---------------------------------------------------------------------------
__global__ __launch_bounds__(256) void k_head(
    const unsigned short* __restrict__ A,    // [2048][256] bf16 (padded)
    const unsigned short* __restrict__ Bw,   // [32000][256] bf16
    const float* __restrict__ bias,          // [32000]
    float* __restrict__ out,                 // [2032][32000]
    int M)
{
  __shared__ unsigned short Bs[32768];       // 64 KB
  const int bid = blockIdx.x;
  const int mt = bid % 16, nt = bid / 16;
  const int tid = threadIdx.x;
  const int lane = tid & 63, w = tid >> 6;
  const int l15 = lane & 15, l4 = lane >> 4;

  const long nbase = (long)nt * 128;
  #pragma unroll
  for (int it=0; it<16; ++it) {
    int idx = it*256 + tid;                  // 0..4095 16B-chunks
    int rr = idx >> 5;                       // 0..127
    int ch = idx & 31;
    int sch = ch ^ (rr & 7);
    u32x4 v = *(const u32x4*)(Bw + (nbase+rr)*256 + sch*8);
    *(u32x4*)&Bs[(long)idx*8] = v;
  }
  __syncthreads();

  const int m0 = mt*128 + w*32;
  const int arow0 = m0 + l15, arow1 = arow0 + 16;
  const int kc = l4 * 8;

  f32x4 acc[2][8];
  #pragma unroll
  for (int rt=0; rt<2; ++rt)
    #pragma unroll
    for (int ct=0; ct<8; ++ct){ f32x4 z4={0.f,0.f,0.f,0.f}; acc[rt][ct]=z4; }

  #pragma unroll
  for (int kb=0; kb<8; ++kb) {
    short8 a0 = *(const short8*)(A + (long)arow0*256 + kb*32 + kc);
    short8 a1 = *(const short8*)(A + (long)arow1*256 + kb*32 + kc);
    int c = kb*4 + l4;
    #pragma unroll
    for (int ct=0; ct<8; ++ct) {
      int n_local = ct*16 + l15;
      int sc = c ^ (n_local & 7);
      short8 bf = *(const short8*)&Bs[((long)n_local*32 + sc)*8];
      acc[0][ct] = mfma16(a0, bf, acc[0][ct]);
      acc[1][ct] = mfma16(a1, bf, acc[1][ct]);
    }
  }

  #pragma unroll
  for (int ct=0; ct<8; ++ct) {
    int n_g = nt*128 + ct*16 + l15;
    float bv = bias[n_g];
    #pragma unroll
    for (int rt=0; rt<2; ++rt) {
      #pragma unroll
      for (int q=0; q<4; ++q) {
        int r_g = m0 + rt*16 + l4*4 + q;
        if (r_g < M) out[(long)r_g*32000 + n_g] = acc[rt][ct][q] + bv;
      }
    }
  }
}

// ---------------------------------------------------------------------------
extern "C" void kernel_launch(void* const* d_in, const int* in_sizes, int n_in,
                              void* d_out, int out_size, void* d_ws, size_t ws_size,
                              hipStream_t stream)
{
  (void)in_sizes; (void)n_in; (void)out_size; (void)ws_size;
  const int*   ctx_ids  = (const int*)  d_in[0];
  const int*   ctx_mask = (const int*)  d_in[1];
  const float* img      = (const float*)d_in[2];
  const int*   tgt_ids  = (const int*)  d_in[3];
  const float* emb_text = (const float*)d_in[4];
  const float* Wih_t    = (const float*)d_in[5];
  const float* Whh_t    = (const float*)d_in[6];
  const float* bih_t    = (const float*)d_in[7];
  const float* bhh_t    = (const float*)d_in[8];
  const float* fuse_W   = (const float*)d_in[9];
  const float* fuse_b   = (const float*)d_in[10];
  const float* mem_init = (const float*)d_in[11];
  const float* Wih_c    = (const float*)d_in[12];
  const float* Whh_c    = (const float*)d_in[13];
  const float* bih_c    = (const float*)d_in[14];
  const float* bhh_c    = (const float*)d_in[15];
  const float* tok_emb  = (const float*)d_in[16];
  const float* Wih_d    = (const float*)d_in[17];
  const float* Whh_d    = (const float*)d_in[18];
  const float* bih_d    = (const float*)d_in[19];
  const float* bhh_d    = (const float*)d_in[20];
  const float* head_W   = (const float*)d_in[21];
  const float* head_b   = (const float*)d_in[22];
  float* out = (float*)d_out;
  char* ws = (char*)d_ws;

  size_t o = 0;
  auto alloc = [&](size_t bytes){ size_t r = o; o += (bytes + 255) & ~(size_t)255; return r; };
  unsigned short* wWih_t = (unsigned short*)(ws + alloc(768*256*2));
  unsigned short* wWhh_t = (unsigned short*)(ws + alloc(768*256*2));
  unsigned short* wWih_c = (unsigned short*)(ws + alloc(768*256*2));
  unsigned short* wWhh_c = (unsigned short*)(ws + alloc(768*256*2));
  unsigned short* wWih_d = (unsigned short*)(ws + alloc(768*256*2));
  unsigned short* wWhh_d = (unsigned short*)(ws + alloc(768*256*2));
  unsigned short* wFuse  = (unsigned short*)(ws + alloc(256*768*2));
  unsigned short* wHead  = (unsigned short*)(ws + alloc((size_t)32000*256*2));
  unsigned short* xg_t   = (unsigned short*)(ws + alloc((size_t)16384*768*2));
  unsigned short* xg_c   = (unsigned short*)(ws + alloc((size_t)512*768*2));
  unsigned short* xg_d   = (unsigned short*)(ws + alloc((size_t)2032*768*2));
  float*          tvec   = (float*)(ws + alloc((size_t)512*256*4));
  float*          zbuf   = (float*)(ws + alloc((size_t)512*256*4));
  float*          z2buf  = (float*)(ws + alloc((size_t)512*256*4));
  unsigned short* outsb  = (unsigned short*)(ws + alloc((size_t)2048*256*2));
  unsigned short* hbctx  = (unsigned short*)(ws + alloc((size_t)2*32*4096*2));
  unsigned short* hbg2   = (unsigned short*)(ws + alloc((size_t)2*4096*2));
  unsigned short* hbdec  = (unsigned short*)(ws + alloc((size_t)2*4096*2));
  int*            flags  = (int*)(ws + alloc((size_t)(32*33 + 33 + 128)*4));
  int* flg_ctx = flags;
  int* flg_g2  = flags + 32*33;
  int* flg_dec = flg_g2 + 33;

  // 0) weights -> bf16; zero sync flags (graph-replay safe)
  k_cvt<<<2048, 256, 0, stream>>>(head_W, wHead,
      Wih_t, Whh_t, Wih_c, Whh_c, Wih_d, Whh_d, fuse_W,
      wWih_t, wWhh_t, wWih_c, wWhh_c, wWih_d, wWhh_d, wFuse);
  (void)hipMemsetAsync(flags, 0, (size_t)(32*33 + 33 + 128)*4, stream);

  // 1) xg for ctx text GRU: rows = (b*K+k)*L + l = 16384
  k_gemm<32,32,0><<<dim3(256,6), 256, 0, stream>>>(
      emb_text, 256, nullptr, 0, 256, ctx_ids, wWih_t, bih_t, 16384, 256, xg_t, 768);

  // 1b) xg for decoder (independent): rows = b*127 + t = 2032
  k_gemm<127,128,0><<<dim3(32,6), 256, 0, stream>>>(
      tok_emb, 256, nullptr, 0, 256, tgt_ids, wWih_d, bih_d, 2032, 256, xg_d, 768);

  // 2) ctx text GRU (masked), 32 groups x 8 blocks -> tvec (f32)
  k_gruD<<<256, 128, 0, stream>>>(wWhh_t, bhh_t, xg_t, ctx_mask, 0,
                                  hbctx, flg_ctx, nullptr, tvec, nullptr, 32, 32);

  // 3) fuse: z = tanh([tvec|img] @ fuse_W^T + fuse_b), 512x256
  k_gemm<1,1,1><<<dim3(8,2), 256, 0, stream>>>(
      tvec, 256, img, 512, 256, nullptr, wFuse, fuse_b, 512, 768, zbuf, 256);

  // 4) memory scan -> z2
  k_mem<<<16, 64, 0, stream>>>(zbuf, mem_init, z2buf);

  // 5) xg for ctx GRU2 from z2 (rows b*32+t = 512)
  k_gemm<1,1,0><<<dim3(8,6), 256, 0, stream>>>(
      z2buf, 256, nullptr, 0, 256, nullptr, wWih_c, bih_c, 512, 256, xg_c, 768);

  // 6) ctx GRU2 (1 group x 8 blocks); final h -> decoder hbuf buf0 (bf16)
  k_gruD<<<8, 128, 0, stream>>>(wWhh_c, bhh_c, xg_c, nullptr, 0,
                                hbg2, flg_g2, nullptr, nullptr, hbdec, 32, 1);

  // 7) decoder GRU (1 group x 8 blocks), h0 preloaded -> outs bf16
  k_gruD<<<8, 128, 0, stream>>>(wWhh_d, bhh_d, xg_d, nullptr, 1,
                                hbdec, flg_dec, outsb, nullptr, nullptr, 127, 1);

  // 8) head: logits
  k_head<<<4000, 256, 0, stream>>>(outsb, wHead, head_b, out, 2032);
}

// Round 8
// 808.583 us; speedup vs baseline: 1.7350x; 1.7350x over previous
//
#include <hip/hip_runtime.h>
#include <hip/hip_bf16.h>

typedef __attribute__((ext_vector_type(4))) float f32x4;
typedef __attribute__((ext_vector_type(8))) short short8;
typedef __attribute__((ext_vector_type(4))) unsigned int u32x4;
typedef __attribute__((ext_vector_type(4))) unsigned short u16x4;

static __device__ __forceinline__ unsigned short f2bf(float f){
  unsigned u = __builtin_bit_cast(unsigned, f);
  u += 0x7FFFu + ((u >> 16) & 1u);
  return (unsigned short)(u >> 16);
}
static __device__ __forceinline__ float bf2f(unsigned short b){
  return __builtin_bit_cast(float, ((unsigned)b) << 16);
}
static __device__ __forceinline__ f32x4 mfma16(short8 a, short8 b, f32x4 c){
  return __builtin_amdgcn_mfma_f32_16x16x32_bf16(a, b, c, 0, 0, 0);
}
static __device__ __forceinline__ float rcpf(float x){ return __builtin_amdgcn_rcpf(x); }
static __device__ __forceinline__ float sigf(float x){ return rcpf(1.f + __expf(-x)); }
static __device__ __forceinline__ float tanhfast(float x){
  float e = __expf(2.f*x);
  return (e - 1.f) * rcpf(e + 1.f);
}

// ---------------------------------------------------------------------------
// fp32 -> bf16 weight conversion (head_W + 7 small matrices of 196608 elems)
// ---------------------------------------------------------------------------
__global__ __launch_bounds__(256) void k_cvt(
    const float* __restrict__ sh, unsigned short* __restrict__ dh,
    const float* __restrict__ s0, const float* __restrict__ s1,
    const float* __restrict__ s2, const float* __restrict__ s3,
    const float* __restrict__ s4, const float* __restrict__ s5,
    const float* __restrict__ s6,
    unsigned short* __restrict__ d0, unsigned short* __restrict__ d1,
    unsigned short* __restrict__ d2, unsigned short* __restrict__ d3,
    unsigned short* __restrict__ d4, unsigned short* __restrict__ d5,
    unsigned short* __restrict__ d6)
{
  const long NH4 = 2048000;   // head: 8,192,000 floats / 4
  const long NS4 = 49152;     // small: 196,608 floats / 4
  const long total = NH4 + 7*NS4;
  for (long idx = (long)blockIdx.x*blockDim.x + threadIdx.x; idx < total;
       idx += (long)gridDim.x*blockDim.x) {
    const float* s; unsigned short* d; long off;
    if (idx < NH4) { s = sh; d = dh; off = idx; }
    else {
      long r = idx - NH4; int mat = (int)(r / NS4); off = r - (long)mat*NS4;
      switch (mat) {
        case 0: s=s0; d=d0; break;  case 1: s=s1; d=d1; break;
        case 2: s=s2; d=d2; break;  case 3: s=s3; d=d3; break;
        case 4: s=s4; d=d4; break;  case 5: s=s5; d=d5; break;
        default: s=s6; d=d6; break;
      }
    }
    f32x4 v = ((const f32x4*)s)[off];
    u16x4 o2;
    o2[0]=f2bf(v[0]); o2[1]=f2bf(v[1]); o2[2]=f2bf(v[2]); o2[3]=f2bf(v[3]);
    ((u16x4*)d)[off] = o2;
  }
}

// ---------------------------------------------------------------------------
// Generic MFMA GEMM: out[M][N] = gatherA[M][Ktot] @ W[N][Ktot]^T + bias
// ---------------------------------------------------------------------------
template<int TN, int TS, int EPI>
__global__ __launch_bounds__(256) void k_gemm(
    const float* __restrict__ tabA, int ldA,
    const float* __restrict__ tabB2, int ldB2, int K1,
    const int* __restrict__ ids,
    const unsigned short* __restrict__ W,   // [N][Ktot] bf16
    const float* __restrict__ bias,         // [N]
    int M, int Ktot,
    void* __restrict__ outp, int ldOut)
{
  const int bm = blockIdx.x, bn = blockIdx.y;
  const int tid = threadIdx.x;
  const int lane = tid & 63, w = tid >> 6;
  const int l15 = lane & 15, l4 = lane >> 4;

  const int r_g = bm*64 + w*16 + l15;
  const int r_c = (r_g < M) ? r_g : (M-1);
  long row_src;
  if (ids) { int ii = (r_c / TN) * TS + (r_c % TN); row_src = ids[ii]; }
  else row_src = r_c;

  const int kchunk = l4 * 8;
  const int ncol0 = bn*128 + l15;

  f32x4 acc[8];
  #pragma unroll
  for (int i=0;i<8;i++){ f32x4 z4 = {0.f,0.f,0.f,0.f}; acc[i]=z4; }

  const int KB = Ktot >> 5;
  for (int kb = 0; kb < KB; ++kb) {
    int k = kb*32 + kchunk;
    const float* ap;
    if (tabB2 && k >= K1) ap = tabB2 + row_src*(long)ldB2 + (k - K1);
    else                  ap = tabA  + row_src*(long)ldA  + k;
    f32x4 a0 = *(const f32x4*)ap;
    f32x4 a1 = *(const f32x4*)(ap + 4);
    short8 afr;
    afr[0]=(short)f2bf(a0[0]); afr[1]=(short)f2bf(a0[1]);
    afr[2]=(short)f2bf(a0[2]); afr[3]=(short)f2bf(a0[3]);
    afr[4]=(short)f2bf(a1[0]); afr[5]=(short)f2bf(a1[1]);
    afr[6]=(short)f2bf(a1[2]); afr[7]=(short)f2bf(a1[3]);
    #pragma unroll
    for (int ct=0; ct<8; ++ct) {
      int n = ncol0 + ct*16;
      short8 bfr = *(const short8*)(W + (long)n*Ktot + k);
      acc[ct] = mfma16(afr, bfr, acc[ct]);
    }
  }

  #pragma unroll
  for (int ct=0; ct<8; ++ct) {
    int n = ncol0 + ct*16;
    float bv = bias[n];
    #pragma unroll
    for (int q=0; q<4; ++q) {
      int rr = bm*64 + w*16 + l4*4 + q;
      if (rr < M) {
        float v = acc[ct][q] + bv;
        if (EPI == 1) ((float*)outp)[(long)rr*ldOut + n] = tanhfast(v);
        else ((unsigned short*)outp)[(long)rr*ldOut + n] = f2bf(v);
      }
    }
  }
}

// ---------------------------------------------------------------------------
// GRU recurrence, single block per 16-row group, 512 threads / 8 waves.
//   Wave w owns units [w*32, w*32+32) x all 3 gates (gate-colocated cols):
//   MFMA C layout (col=lane&15) makes gate math fully LANE-LOCAL -> no hg
//   LDS round-trip, ONE barrier/step (h_bf double-buffered by parity).
//   Whh residency (the r2-r7 saga: register pins remat'd, AGPR asm corrupted,
//   cross-block LDS needed 9450cy/step sync):
//     - gate r tiles (2/wave) -> 128KB LDS, deterministic residency
//     - gate z,n tiles (4/wave) -> 128 VGPRs, loaded VOLATILE (remat illegal)
//   Pressure ~225 < 256 cap (512thr @ 2 waves/SIMD).
// ---------------------------------------------------------------------------
__global__ __launch_bounds__(512, 2) void k_gru(
    const unsigned short* __restrict__ Whh,  // [768][256] bf16
    const float* __restrict__ bhh,           // [768]
    const unsigned short* __restrict__ xg,   // [(grow*T+t)][768] bf16 (bih inc.)
    const int* __restrict__ mask,            // [(grow*T+t)] or null
    const unsigned short* __restrict__ h0bf, // [16][256] bf16 or null
    float* __restrict__ hNf,                 // [grow][256] f32 or null
    unsigned short* __restrict__ hNbf,       // [16][256] bf16 or null
    unsigned short* __restrict__ outs,       // [(grow*T+t)][256] bf16 or null
    int T)
{
  __shared__ unsigned short Wl[8*2*8*64*8];  // [w][ts][kb][lane]x8 = 128KB
  __shared__ unsigned short hb[2][16][264];  // double-buffered h, 16.9KB

  const int tid = threadIdx.x;
  const int w = tid >> 6, lane = tid & 63;
  const int l15 = lane & 15, l4 = lane >> 4;
  const int rowbase = blockIdx.x * 16;

  // ---- stage gate-r tiles (ts=0,1) into LDS ----
  #pragma unroll
  for (int ts=0; ts<2; ++ts)
    #pragma unroll
    for (int kb=0; kb<8; ++kb)
      *(short8*)&Wl[(((w*2+ts)*8+kb)*64 + lane)*8] =
        *(const short8*)(Whh + (long)(w*32 + ts*16 + l15)*256 + kb*32 + l4*8);

  // ---- gate-z/n tiles into registers via volatile loads (no remat) ----
  short8 Bf[4][8];
  #pragma unroll
  for (int j=0; j<4; ++j)
    #pragma unroll
    for (int kb=0; kb<8; ++kb) {
      const volatile u32x4* p = (const volatile u32x4*)
        (Whh + (long)((1+(j>>1))*256 + w*32 + (j&1)*16 + l15)*256 + kb*32 + l4*8);
      u32x4 raw = *p;
      Bf[j][kb] = __builtin_bit_cast(short8, raw);
    }

  float b_r[2], b_z[2], b_n[2];
  #pragma unroll
  for (int s=0; s<2; ++s) {
    int u = w*32 + s*16 + l15;
    b_r[s] = bhh[u]; b_z[s] = bhh[256+u]; b_n[s] = bhh[512+u];
  }

  // ---- init h: lane owns (4 rows l4*4+q) x (2 units) ----
  float h[2][4];
  #pragma unroll
  for (int s=0; s<2; ++s) {
    int u = w*32 + s*16 + l15;
    #pragma unroll
    for (int q=0; q<4; ++q) {
      int r = l4*4 + q;
      float hv = h0bf ? bf2f(h0bf[r*256 + u]) : 0.f;
      h[s][q] = hv;
      hb[0][r][u] = f2bf(hv);
    }
  }
  __syncthreads();

  for (int t=0; t<T; ++t) {
    const int p = t & 1;

    // ---- xg gather (h-independent; latency hides under MFMA) ----
    unsigned short xrv[2][4], xzv[2][4], xnv[2][4];
    int mok[4];
    #pragma unroll
    for (int q=0; q<4; ++q) {
      long xrow = (long)(rowbase + l4*4 + q)*T + t;
      mok[q] = mask ? mask[xrow] : 1;
      const unsigned short* xp = xg + xrow*768;
      #pragma unroll
      for (int s=0; s<2; ++s) {
        int u = w*32 + s*16 + l15;
        xrv[s][q] = xp[u]; xzv[s][q] = xp[256+u]; xnv[s][q] = xp[512+u];
      }
    }

    // ---- MFMA: hg for this wave's 32 units x 3 gates ----
    f32x4 aR0={0.f,0.f,0.f,0.f}, aR1={0.f,0.f,0.f,0.f};
    f32x4 aZ0={0.f,0.f,0.f,0.f}, aZ1={0.f,0.f,0.f,0.f};
    f32x4 aN0={0.f,0.f,0.f,0.f}, aN1={0.f,0.f,0.f,0.f};
    #pragma unroll
    for (int kb=0; kb<8; ++kb) {
      short8 af = *(const short8*)&hb[p][l15][kb*32 + l4*8];
      aR0 = mfma16(af, *(const short8*)&Wl[(((w*2+0)*8+kb)*64+lane)*8], aR0);
      aR1 = mfma16(af, *(const short8*)&Wl[(((w*2+1)*8+kb)*64+lane)*8], aR1);
      aZ0 = mfma16(af, Bf[0][kb], aZ0);
      aZ1 = mfma16(af, Bf[1][kb], aZ1);
      aN0 = mfma16(af, Bf[2][kb], aN0);
      aN1 = mfma16(af, Bf[3][kb], aN1);
    }

    // ---- gates: lane-local (col=lane&15, row=l4*4+q) ----
    #pragma unroll
    for (int s=0; s<2; ++s) {
      int u = w*32 + s*16 + l15;
      f32x4 aR = s ? aR1 : aR0;
      f32x4 aZ = s ? aZ1 : aZ0;
      f32x4 aN = s ? aN1 : aN0;
      #pragma unroll
      for (int q=0; q<4; ++q) {
        int r = l4*4 + q;
        float rr = sigf(bf2f(xrv[s][q]) + aR[q] + b_r[s]);
        float zz = sigf(bf2f(xzv[s][q]) + aZ[q] + b_z[s]);
        float nn = tanhfast(bf2f(xnv[s][q]) + rr*(aN[q] + b_n[s]));
        float hv = nn + zz*(h[s][q] - nn);
        if (!mok[q]) hv = h[s][q];
        h[s][q] = hv;
        unsigned short hbv = f2bf(hv);
        hb[p^1][r][u] = hbv;
        if (outs) {
          long xrow = (long)(rowbase + r)*T + t;
          outs[xrow*256 + u] = hbv;
        }
      }
    }
    __syncthreads();
  }

  if (hNf || hNbf) {
    #pragma unroll
    for (int s=0; s<2; ++s) {
      int u = w*32 + s*16 + l15;
      #pragma unroll
      for (int q=0; q<4; ++q) {
        int r = l4*4 + q;
        if (hNf)  hNf[(long)(rowbase+r)*256 + u] = h[s][q];
        if (hNbf) hNbf[r*256 + u] = f2bf(h[s][q]);
      }
    }
  }
}

// ---------------------------------------------------------------------------
// Memory scan: per batch b (block, 1 wave): 32 steps of attention-write memory.
// ---------------------------------------------------------------------------
__global__ __launch_bounds__(64) void k_mem(
    const float* __restrict__ z,         // [512][256] rows b*32+t
    const float* __restrict__ mem_init,  // [16][256]
    float* __restrict__ z2)              // [512][256]
{
  const int b = blockIdx.x;
  const int lane = threadIdx.x;
  float mem[16][4];
  #pragma unroll
  for (int m=0; m<16; ++m) {
    f32x4 v = *(const f32x4*)(mem_init + m*256 + lane*4);
    mem[m][0]=v[0]; mem[m][1]=v[1]; mem[m][2]=v[2]; mem[m][3]=v[3];
  }
  for (int t=0; t<32; ++t) {
    f32x4 q = *(const f32x4*)(z + ((long)b*32 + t)*256 + lane*4);
    float s[16];
    #pragma unroll
    for (int m=0; m<16; ++m)
      s[m] = mem[m][0]*q[0] + mem[m][1]*q[1] + mem[m][2]*q[2] + mem[m][3]*q[3];
    #pragma unroll
    for (int st=1; st<64; st<<=1) {
      #pragma unroll
      for (int m=0; m<16; ++m) s[m] += __shfl_xor(s[m], st, 64);
    }
    float mx = -1e30f;
    #pragma unroll
    for (int m=0; m<16; ++m) { s[m] *= 0.0625f; mx = fmaxf(mx, s[m]); }
    float sum = 0.f;
    #pragma unroll
    for (int m=0; m<16; ++m) { s[m] = __expf(s[m]-mx); sum += s[m]; }
    float inv = rcpf(sum);
    f32x4 ro = {0.f,0.f,0.f,0.f};
    #pragma unroll
    for (int m=0; m<16; ++m) {
      float wm = s[m]*inv;
      #pragma unroll
      for (int c=0; c<4; ++c) {
        ro[c] += wm * mem[m][c];
        mem[m][c] += wm * (q[c] - mem[m][c]);
      }
    }
    f32x4 o = q + ro;
    *(f32x4*)(z2 + ((long)b*32 + t)*256 + lane*4) = o;
  }
}

// ---------------------------------------------------------------------------
// Head GEMM: out[2032][32000] = A[2032][256]bf16 @ Bw[32000][256]^T + bias
// ---------------------------------------------------------------------------
__global__ __launch_bounds__(256) void k_head(
    const unsigned short* __restrict__ A,    // [2048][256] bf16 (padded)
    const unsigned short* __restrict__ Bw,   // [32000][256] bf16
    const float* __restrict__ bias,          // [32000]
    float* __restrict__ out,                 // [2032][32000]
    int M)
{
  __shared__ unsigned short Bs[32768];       // 64 KB
  const int bid = blockIdx.x;
  const int mt = bid % 16, nt = bid / 16;
  const int tid = threadIdx.x;
  const int lane = tid & 63, w = tid >> 6;
  const int l15 = lane & 15, l4 = lane >> 4;

  const long nbase = (long)nt * 128;
  #pragma unroll
  for (int it=0; it<16; ++it) {
    int idx = it*256 + tid;                  // 0..4095 16B-chunks
    int rr = idx >> 5;                       // 0..127
    int ch = idx & 31;
    int sch = ch ^ (rr & 7);
    u32x4 v = *(const u32x4*)(Bw + (nbase+rr)*256 + sch*8);
    *(u32x4*)&Bs[(long)idx*8] = v;
  }
  __syncthreads();

  const int m0 = mt*128 + w*32;
  const int arow0 = m0 + l15, arow1 = arow0 + 16;
  const int kc = l4 * 8;

  f32x4 acc[2][8];
  #pragma unroll
  for (int rt=0; rt<2; ++rt)
    #pragma unroll
    for (int ct=0; ct<8; ++ct){ f32x4 z4={0.f,0.f,0.f,0.f}; acc[rt][ct]=z4; }

  #pragma unroll
  for (int kb=0; kb<8; ++kb) {
    short8 a0 = *(const short8*)(A + (long)arow0*256 + kb*32 + kc);
    short8 a1 = *(const short8*)(A + (long)arow1*256 + kb*32 + kc);
    int c = kb*4 + l4;
    #pragma unroll
    for (int ct=0; ct<8; ++ct) {
      int n_local = ct*16 + l15;
      int sc = c ^ (n_local & 7);
      short8 bf = *(const short8*)&Bs[((long)n_local*32 + sc)*8];
      acc[0][ct] = mfma16(a0, bf, acc[0][ct]);
      acc[1][ct] = mfma16(a1, bf, acc[1][ct]);
    }
  }

  #pragma unroll
  for (int ct=0; ct<8; ++ct) {
    int n_g = nt*128 + ct*16 + l15;
    float bv = bias[n_g];
    #pragma unroll
    for (int rt=0; rt<2; ++rt) {
      #pragma unroll
      for (int q=0; q<4; ++q) {
        int r_g = m0 + rt*16 + l4*4 + q;
        if (r_g < M) out[(long)r_g*32000 + n_g] = acc[rt][ct][q] + bv;
      }
    }
  }
}

// ---------------------------------------------------------------------------
extern "C" void kernel_launch(void* const* d_in, const int* in_sizes, int n_in,
                              void* d_out, int out_size, void* d_ws, size_t ws_size,
                              hipStream_t stream)
{
  (void)in_sizes; (void)n_in; (void)out_size; (void)ws_size;
  const int*   ctx_ids  = (const int*)  d_in[0];
  const int*   ctx_mask = (const int*)  d_in[1];
  const float* img      = (const float*)d_in[2];
  const int*   tgt_ids  = (const int*)  d_in[3];
  const float* emb_text = (const float*)d_in[4];
  const float* Wih_t    = (const float*)d_in[5];
  const float* Whh_t    = (const float*)d_in[6];
  const float* bih_t    = (const float*)d_in[7];
  const float* bhh_t    = (const float*)d_in[8];
  const float* fuse_W   = (const float*)d_in[9];
  const float* fuse_b   = (const float*)d_in[10];
  const float* mem_init = (const float*)d_in[11];
  const float* Wih_c    = (const float*)d_in[12];
  const float* Whh_c    = (const float*)d_in[13];
  const float* bih_c    = (const float*)d_in[14];
  const float* bhh_c    = (const float*)d_in[15];
  const float* tok_emb  = (const float*)d_in[16];
  const float* Wih_d    = (const float*)d_in[17];
  const float* Whh_d    = (const float*)d_in[18];
  const float* bih_d    = (const float*)d_in[19];
  const float* bhh_d    = (const float*)d_in[20];
  const float* head_W   = (const float*)d_in[21];
  const float* head_b   = (const float*)d_in[22];
  float* out = (float*)d_out;
  char* ws = (char*)d_ws;

  size_t o = 0;
  auto alloc = [&](size_t bytes){ size_t r = o; o += (bytes + 255) & ~(size_t)255; return r; };
  unsigned short* wWih_t = (unsigned short*)(ws + alloc(768*256*2));
  unsigned short* wWhh_t = (unsigned short*)(ws + alloc(768*256*2));
  unsigned short* wWih_c = (unsigned short*)(ws + alloc(768*256*2));
  unsigned short* wWhh_c = (unsigned short*)(ws + alloc(768*256*2));
  unsigned short* wWih_d = (unsigned short*)(ws + alloc(768*256*2));
  unsigned short* wWhh_d = (unsigned short*)(ws + alloc(768*256*2));
  unsigned short* wFuse  = (unsigned short*)(ws + alloc(256*768*2));
  unsigned short* wHead  = (unsigned short*)(ws + alloc((size_t)32000*256*2));
  unsigned short* xg_t   = (unsigned short*)(ws + alloc((size_t)16384*768*2));
  unsigned short* xg_c   = (unsigned short*)(ws + alloc((size_t)512*768*2));
  unsigned short* xg_d   = (unsigned short*)(ws + alloc((size_t)2032*768*2));
  float*          tvec   = (float*)(ws + alloc((size_t)512*256*4));
  float*          zbuf   = (float*)(ws + alloc((size_t)512*256*4));
  float*          z2buf  = (float*)(ws + alloc((size_t)512*256*4));
  unsigned short* outsb  = (unsigned short*)(ws + alloc((size_t)2048*256*2));
  unsigned short* hbdec  = (unsigned short*)(ws + alloc((size_t)16*256*2));

  // 0) weights -> bf16
  k_cvt<<<2048, 256, 0, stream>>>(head_W, wHead,
      Wih_t, Whh_t, Wih_c, Whh_c, Wih_d, Whh_d, fuse_W,
      wWih_t, wWhh_t, wWih_c, wWhh_c, wWih_d, wWhh_d, wFuse);

  // 1) xg for ctx text GRU: rows = (b*K+k)*L + l = 16384
  k_gemm<32,32,0><<<dim3(256,6), 256, 0, stream>>>(
      emb_text, 256, nullptr, 0, 256, ctx_ids, wWih_t, bih_t, 16384, 256, xg_t, 768);

  // 1b) xg for decoder (independent): rows = b*127 + t = 2032
  k_gemm<127,128,0><<<dim3(32,6), 256, 0, stream>>>(
      tok_emb, 256, nullptr, 0, 256, tgt_ids, wWih_d, bih_d, 2032, 256, xg_d, 768);

  // 2) ctx text GRU (masked), 32 groups of 16 rows -> tvec (f32)
  k_gru<<<32, 512, 0, stream>>>(wWhh_t, bhh_t, xg_t, ctx_mask,
                                nullptr, tvec, nullptr, nullptr, 32);

  // 3) fuse: z = tanh([tvec|img] @ fuse_W^T + fuse_b), 512x256
  k_gemm<1,1,1><<<dim3(8,2), 256, 0, stream>>>(
      tvec, 256, img, 512, 256, nullptr, wFuse, fuse_b, 512, 768, zbuf, 256);

  // 4) memory scan -> z2
  k_mem<<<16, 64, 0, stream>>>(zbuf, mem_init, z2buf);

  // 5) xg for ctx GRU2 from z2 (rows b*32+t = 512)
  k_gemm<1,1,0><<<dim3(8,6), 256, 0, stream>>>(
      z2buf, 256, nullptr, 0, 256, nullptr, wWih_c, bih_c, 512, 256, xg_c, 768);

  // 6) ctx GRU2 -> h0 (bf16) for decoder
  k_gru<<<1, 512, 0, stream>>>(wWhh_c, bhh_c, xg_c, nullptr,
                               nullptr, nullptr, hbdec, nullptr, 32);

  // 7) decoder GRU, h0 preloaded -> outs bf16
  k_gru<<<1, 512, 0, stream>>>(wWhh_d, bhh_d, xg_d, nullptr,
                               hbdec, nullptr, nullptr, outsb, 127);

  // 8) head: logits
  k_head<<<4000, 256, 0, stream>>>(outsb, wHead, head_b, out, 2032);
}